// Round 12
// baseline (335.028 us; speedup 1.0000x reference)
//
#include <hip/hip_runtime.h>
#include <hip/hip_fp16.h>

static inline size_t align256(size_t x) { return (x + 255) & ~size_t(255); }

#define CAP 36864   // per-bucket capacity: mean 32768, sigma ~181 -> +22 sigma

// ---- scatter edges into fixed-capacity buckets, 4B packed (dst_local<<18 | src) ----
__global__ __launch_bounds__(512) void k_scatter(const int* __restrict__ ei,
                                                 int* __restrict__ bcursor,
                                                 unsigned* __restrict__ bdata, int E) {
    __shared__ int lcount[256];
    __shared__ int gbase[256];
    int t = threadIdx.x;
    if (t < 256) lcount[t] = 0;
    __syncthreads();
    int chunk = blockIdx.x * 8192;
    int srcv[16], bkt[16], rank[16], dl[16];
#pragma unroll
    for (int k = 0; k < 16; ++k) {
        int e = chunk + k * 512 + t;
        bkt[k] = -1;
        if (e < E) {
            int sv = ei[e], d = ei[E + e];
            int b = d >> 10;
            srcv[k] = sv; bkt[k] = b; dl[k] = d & 1023;
            rank[k] = atomicAdd(&lcount[b], 1);
        }
    }
    __syncthreads();
    if (t < 256) {
        int c = lcount[t];
        gbase[t] = t * CAP + (c ? atomicAdd(&bcursor[t], c) : 0);
    }
    __syncthreads();
#pragma unroll
    for (int k = 0; k < 16; ++k) {
        if (bkt[k] >= 0)
            bdata[gbase[bkt[k]] + rank[k]] = ((unsigned)dl[k] << 18) | (unsigned)srcv[k];
    }
}

// ---- scan bucket counts -> true cumulative bases ----
__global__ void k_bscan2(const int* __restrict__ bcursor, int* __restrict__ bbase,
                         int NBv, int E) {
    __shared__ int lds[256];
    int t = threadIdx.x;
    int v = (t < NBv) ? bcursor[t] : 0;
    lds[t] = v;
    __syncthreads();
    for (int off = 1; off < 256; off <<= 1) {
        int x = (t >= off) ? lds[t - off] : 0;
        __syncthreads();
        lds[t] += x;
        __syncthreads();
    }
    if (t < NBv) bbase[t] = lds[t] - v;
    if (t == 0) bbase[NBv] = E;
}

// ---- per-bucket CSR build: LDS-staged col placement (no random global writes) ----
__global__ __launch_bounds__(1024) void k_build(const unsigned* __restrict__ bdata,
                                                const int* __restrict__ bbase,
                                                int* __restrict__ row_ptr,
                                                float* __restrict__ dinv,
                                                int* __restrict__ col,
                                                const float* __restrict__ x,
                                                float2* __restrict__ xt,
                                                int N, int E, int NBv) {
    __shared__ int curs[1024];
    __shared__ int sums[256];
    __shared__ int stage[CAP];          // 147 KB; first 1024 ints double as hist
    int* hist = stage;                  // alias: hist is dead before stage is written
    int bkt = blockIdx.x;
    int t = threadIdx.x;
    int tb = bbase[bkt];
    int count = bbase[bkt + 1] - tb;
    int fs = bkt * CAP;                 // fixed storage base
    int node0 = bkt << 10;
    int nn = N - node0; if (nn > 1024) nn = 1024;
    hist[t] = 0;
    __syncthreads();
    for (int e = t; e < count; e += 1024)
        atomicAdd(&hist[bdata[fs + e] >> 18], 1);
    __syncthreads();
    int v0 = 0, v1 = 0, v2 = 0, v3 = 0, s = 0;
    if (t < 256) {
        int b4 = t * 4;
        v0 = hist[b4]; v1 = hist[b4 + 1]; v2 = hist[b4 + 2]; v3 = hist[b4 + 3];
        s = v0 + v1 + v2 + v3;
        sums[t] = s;
    }
    __syncthreads();
    for (int off = 1; off < 256; off <<= 1) {
        int xv = 0;
        if (t < 256 && t >= off) xv = sums[t - off];
        __syncthreads();
        if (t < 256) sums[t] += xv;
        __syncthreads();
    }
    if (t < 256) {
        int b4 = t * 4;
        int e0 = sums[t] - s;           // LOCAL offsets within bucket
        int e1 = e0 + v0, e2 = e1 + v1, e3 = e2 + v2;
        curs[b4] = e0; curs[b4 + 1] = e1; curs[b4 + 2] = e2; curs[b4 + 3] = e3;
        if (b4 < nn)     { row_ptr[node0 + b4]     = tb + e0; dinv[node0 + b4]     = rsqrtf((float)v0 + 1.f); }
        if (b4 + 1 < nn) { row_ptr[node0 + b4 + 1] = tb + e1; dinv[node0 + b4 + 1] = rsqrtf((float)v1 + 1.f); }
        if (b4 + 2 < nn) { row_ptr[node0 + b4 + 2] = tb + e2; dinv[node0 + b4 + 2] = rsqrtf((float)v2 + 1.f); }
        if (b4 + 3 < nn) { row_ptr[node0 + b4 + 3] = tb + e3; dinv[node0 + b4 + 3] = rsqrtf((float)v3 + 1.f); }
    }
    if (bkt == NBv - 1 && t == 0) row_ptr[N] = E;
    __syncthreads();                    // hist reads done; stage may be overwritten
    for (int e = t; e < count; e += 1024) {
        unsigned p = bdata[fs + e];     // second read is L2-hot
        int dl = p >> 18;
        int pos = atomicAdd(&curs[dl], 1);
        stage[pos] = (int)(p & 0x3FFFFu);
    }
    __syncthreads();
    for (int i = t; i < count; i += 1024)
        col[tb + i] = stage[i];         // fully coalesced streaming store
    // fused xt epilogue: xt[node] = x[node] * dinv[node]
    for (int i = t; i < nn; i += 1024) {
        int node = node0 + i;
        float d2 = dinv[node];
        xt[node] = make_float2(x[node * 2] * d2, x[node * 2 + 1] * d2);
    }
}

// ================= conv1: 4 lanes/node, 4-deep pipeline, shfl-reduce -> planar fp16 ==
// Writes TWO planar half-tables: htA = features 0..7, htB = features 8..15 (16B rows).
__global__ __launch_bounds__(256) void k_conv1_fused(const int* __restrict__ rp,
                                                     const int* __restrict__ col,
                                                     const float2* __restrict__ xt,
                                                     const float* __restrict__ dinv,
                                                     const float* __restrict__ W1,
                                                     const float* __restrict__ b1,
                                                     uint2* __restrict__ htA,
                                                     uint2* __restrict__ htB, int n) {
    int gt = blockIdx.x * 256 + threadIdx.x;
    int node = gt >> 2;       // 64 nodes per block
    int q = gt & 3;           // lane within quad
    if (node >= n) return;
    int rs = rp[node], re = rp[node + 1];
    float a0 = 0.f, a1 = 0.f;
    int e = rs + q;
    for (; e + 12 < re; e += 16) {
        int c0 = __builtin_nontemporal_load(col + e);
        int c1 = __builtin_nontemporal_load(col + e + 4);
        int c2 = __builtin_nontemporal_load(col + e + 8);
        int c3 = __builtin_nontemporal_load(col + e + 12);
        float2 v0 = xt[c0];
        float2 v1 = xt[c1];
        float2 v2 = xt[c2];
        float2 v3 = xt[c3];
        a0 += (v0.x + v1.x) + (v2.x + v3.x);
        a1 += (v0.y + v1.y) + (v2.y + v3.y);
    }
    for (; e < re; e += 4) {
        float2 v = xt[__builtin_nontemporal_load(col + e)];
        a0 += v.x; a1 += v.y;
    }
    if (q == 0) { float2 sf = xt[node]; a0 += sf.x; a1 += sf.y; }  // self loop
    a0 += __shfl_xor(a0, 1); a0 += __shfl_xor(a0, 2);
    a1 += __shfl_xor(a1, 1); a1 += __shfl_xor(a1, 2);
    float dv = dinv[node];
    a0 *= dv; a1 *= dv;
    int f0 = q * 4;
    float v0 = fmaxf(a0 * W1[f0]     + a1 * W1[16 + f0]     + b1[f0],     0.f) * dv;
    float v1 = fmaxf(a0 * W1[f0 + 1] + a1 * W1[16 + f0 + 1] + b1[f0 + 1], 0.f) * dv;
    float v2 = fmaxf(a0 * W1[f0 + 2] + a1 * W1[16 + f0 + 2] + b1[f0 + 2], 0.f) * dv;
    float v3 = fmaxf(a0 * W1[f0 + 3] + a1 * W1[16 + f0 + 3] + b1[f0 + 3], 0.f) * dv;
    __half2 h0 = __floats2half2_rn(v0, v1);
    __half2 h1 = __floats2half2_rn(v2, v3);
    uint2 w;
    w.x = *reinterpret_cast<unsigned*>(&h0);
    w.y = *reinterpret_cast<unsigned*>(&h1);
    uint2* dst = (q < 2) ? htA : htB;
    dst[(size_t)node * 2 + (q & 1)] = w;   // planar 16B rows
}

// ======== conv2 gather, one 3.2MB half-table per LAUNCH (L2-resident per XCD) ======
// 2 lanes/node x 8B uint2 loads, 16-deep pipeline.
__global__ __launch_bounds__(256) void k_gather2h(const int* __restrict__ rp,
                                                  const int* __restrict__ col,
                                                  const uint2* __restrict__ ht,
                                                  const float* __restrict__ dinv,
                                                  float* __restrict__ agg, int N, int half) {
    int gt = blockIdx.x * 256 + threadIdx.x;
    int node = gt >> 1;      // 128 nodes per block
    int hf = gt & 1;         // which 8B of the 16B row
    if (node >= N) return;
    int rs = rp[node], re = rp[node + 1];
    const uint2* __restrict__ base = ht + hf;   // row stride 2 uint2
    float s0 = 0.f, s1 = 0.f, s2 = 0.f, s3 = 0.f;
    int e = rs;
    for (; e + 16 <= re; e += 16) {
        int c[16];
#pragma unroll
        for (int k = 0; k < 16; ++k) c[k] = __builtin_nontemporal_load(col + e + k);
        uint2 u[16];
#pragma unroll
        for (int k = 0; k < 16; ++k) u[k] = base[(size_t)c[k] * 2];
#pragma unroll
        for (int k = 0; k < 16; ++k) {
            float2 f0 = __half22float2(*reinterpret_cast<__half2*>(&u[k].x));
            float2 f1 = __half22float2(*reinterpret_cast<__half2*>(&u[k].y));
            s0 += f0.x; s1 += f0.y; s2 += f1.x; s3 += f1.y;
        }
    }
    for (; e < re; ++e) {
        uint2 u = base[(size_t)__builtin_nontemporal_load(col + e) * 2];
        float2 f0 = __half22float2(*reinterpret_cast<__half2*>(&u.x));
        float2 f1 = __half22float2(*reinterpret_cast<__half2*>(&u.y));
        s0 += f0.x; s1 += f0.y; s2 += f1.x; s3 += f1.y;
    }
    {   // self loop
        uint2 u = base[(size_t)node * 2];
        float2 f0 = __half22float2(*reinterpret_cast<__half2*>(&u.x));
        float2 f1 = __half22float2(*reinterpret_cast<__half2*>(&u.y));
        s0 += f0.x; s1 += f0.y; s2 += f1.x; s3 += f1.y;
    }
    float dv = dinv[node];
    float* dst = agg + (size_t)node * 16 + half * 8 + hf * 4;
    __builtin_nontemporal_store(s0 * dv, dst);
    __builtin_nontemporal_store(s1 * dv, dst + 1);
    __builtin_nontemporal_store(s2 * dv, dst + 2);
    __builtin_nontemporal_store(s3 * dv, dst + 3);
}

// ================= conv2 transform + relu + segmented pool =================
__global__ __launch_bounds__(256) void k_trans_pool(const float* __restrict__ agg,
                                                    const float* __restrict__ W2,
                                                    const float* __restrict__ b2,
                                                    const int* __restrict__ batch,
                                                    float* __restrict__ gsum, int N) {
    __shared__ float aggs[64][17];
    __shared__ float h2s[64][33];
    __shared__ float w2s[512];   // [16][32] row-major
    __shared__ float b2s[32];
    __shared__ int   bids[64];
    int t = threadIdx.x;
    if (t < 128) ((float4*)w2s)[t] = ((const float4*)W2)[t];
    if (t < 32)  b2s[t] = b2[t];
    int node0 = blockIdx.x * 64;
    if (t < 64)  bids[t] = (node0 + t < N) ? batch[node0 + t] : -1;
    {
        int nl = t >> 2, q = t & 3;
        int node = node0 + nl;
        float4 v = make_float4(0.f, 0.f, 0.f, 0.f);
        if (node < N) v = *(const float4*)(agg + (size_t)node * 16 + (size_t)q * 4);
        int c0 = q * 4;
        aggs[nl][c0] = v.x; aggs[nl][c0 + 1] = v.y;
        aggs[nl][c0 + 2] = v.z; aggs[nl][c0 + 3] = v.w;
    }
    __syncthreads();
    {
        int nl = t >> 2;
        int jq = (t & 3) * 8;
        float o[8];
#pragma unroll
        for (int j = 0; j < 8; ++j) o[j] = b2s[jq + j];
#pragma unroll
        for (int k = 0; k < 16; ++k) {
            float a = aggs[nl][k];
#pragma unroll
            for (int j = 0; j < 8; ++j) o[j] += a * w2s[k * 32 + jq + j];
        }
#pragma unroll
        for (int j = 0; j < 8; ++j) h2s[nl][jq + j] = fmaxf(o[j], 0.f);
    }
    __syncthreads();
    // segmented pooling (batch sorted -> few atomics): 4 segs x 32 feats
    if (t < 128) {
        int j = t & 31, seg = t >> 5;
        int nbeg = seg * 16, nend = nbeg + 16;
        float acc = 0.f;
        int cur = bids[nbeg];
        for (int n2 = nbeg; n2 < nend; ++n2) {
            int b = bids[n2];
            if (b != cur) {
                if (cur >= 0) atomicAdd(&gsum[(size_t)cur * 32 + j], acc);
                acc = 0.f; cur = b;
            }
            if (b >= 0) acc += h2s[n2][j];
        }
        if (cur >= 0) atomicAdd(&gsum[(size_t)cur * 32 + j], acc);
    }
}

// ================= final MLP (graph bounds via binary search on sorted batch) ======
__global__ void k_final(const float* __restrict__ gsum, const int* __restrict__ batch,
                        const float* __restrict__ Wfc1, const float* __restrict__ bfc1,
                        const float* __restrict__ Wfc2, const float* __restrict__ bfc2,
                        float* __restrict__ out, int G, int N) {
    int g = blockIdx.x * blockDim.x + threadIdx.x;
    if (g >= G) return;
    int lo = 0, hi = N;
    while (lo < hi) { int m = (lo + hi) >> 1; if (batch[m] < g) lo = m + 1; else hi = m; }
    int s = lo;
    lo = s; hi = N;
    while (lo < hi) { int m = (lo + hi) >> 1; if (batch[m] < g + 1) lo = m + 1; else hi = m; }
    float cnt = (float)(lo - s);
    float inv = 1.f / fmaxf(cnt, 1.f);
    float p[32];
#pragma unroll
    for (int i = 0; i < 32; ++i) p[i] = gsum[(size_t)g * 32 + i] * inv;
    float o = bfc2[0];
#pragma unroll
    for (int j = 0; j < 16; ++j) {
        float a = bfc1[j];
#pragma unroll
        for (int i = 0; i < 32; ++i) a += p[i] * Wfc1[i * 16 + j];
        o += fmaxf(a, 0.f) * Wfc2[j];
    }
    out[g] = o;
}

extern "C" void kernel_launch(void* const* d_in, const int* in_sizes, int n_in,
                              void* d_out, int out_size, void* d_ws, size_t ws_size,
                              hipStream_t stream) {
    const float* x     = (const float*)d_in[0];
    const int*   ei    = (const int*)d_in[1];
    const int*   batch = (const int*)d_in[2];
    const float* W1    = (const float*)d_in[3];
    const float* b1    = (const float*)d_in[4];
    const float* W2    = (const float*)d_in[5];
    const float* b2    = (const float*)d_in[6];
    const float* Wfc1  = (const float*)d_in[7];
    const float* bfc1  = (const float*)d_in[8];
    const float* Wfc2  = (const float*)d_in[9];
    const float* bfc2  = (const float*)d_in[10];
    float* out = (float*)d_out;

    const int N = in_sizes[0] / 2;      // 200000
    const int E = in_sizes[1] / 2;      // 6400000
    const int G = out_size;             // 1000
    const int NBv = (N + 1023) >> 10;   // 196

    // ---- workspace layout (~77 MB) ----
    char* ws = (char*)d_ws;
    size_t off = 0;
    float* dinv    = (float*)(ws + off); off += align256((size_t)N * 4);
    int*   row_ptr = (int*)(ws + off);   off += align256((size_t)(N + 1) * 4);
    int*   bcursor = (int*)(ws + off);   off += align256(256 * 4);
    int*   bbase   = (int*)(ws + off);   off += align256(257 * 4);
    float* gsum    = (float*)(ws + off); off += align256((size_t)G * 32 * 4);
    float2* xt     = (float2*)(ws + off); off += align256((size_t)N * 8);
    uint2* htA     = (uint2*)(ws + off); off += align256((size_t)N * 16);
    uint2* htB     = (uint2*)(ws + off); off += align256((size_t)N * 16);
    float* agg     = (float*)(ws + off); off += align256((size_t)N * 16 * 4);
    int*   col     = (int*)(ws + off);   off += align256((size_t)E * 4);
    unsigned* bdata = (unsigned*)(ws + off); off += align256((size_t)NBv * CAP * 4);

    const int BS = 256;

    hipMemsetAsync(bcursor, 0, 256 * 4, stream);
    hipMemsetAsync(gsum, 0, (size_t)G * 32 * 4, stream);

    k_scatter<<<(E + 8191) / 8192, 512, 0, stream>>>(ei, bcursor, bdata, E);
    k_bscan2<<<1, 256, 0, stream>>>(bcursor, bbase, NBv, E);
    k_build<<<NBv, 1024, 0, stream>>>(bdata, bbase, row_ptr, dinv, col, x, xt, N, E, NBv);

    k_conv1_fused<<<((size_t)N * 4 + 255) / 256, 256, 0, stream>>>(row_ptr, col, xt, dinv,
                                                                   W1, b1, htA, htB, N);
    k_gather2h<<<((size_t)N * 2 + 255) / 256, 256, 0, stream>>>(row_ptr, col, htA, dinv,
                                                                agg, N, 0);
    k_gather2h<<<((size_t)N * 2 + 255) / 256, 256, 0, stream>>>(row_ptr, col, htB, dinv,
                                                                agg, N, 1);
    k_trans_pool<<<(N + 63) / 64, 256, 0, stream>>>(agg, W2, b2, batch, gsum, N);

    k_final<<<(G + BS - 1) / BS, BS, 0, stream>>>(gsum, batch, Wfc1, bfc1, Wfc2, bfc2,
                                                  out, G, N);
}

// Round 13
// 244.442 us; speedup vs baseline: 1.3706x; 1.3706x over previous
//
#include <hip/hip_runtime.h>
#include <hip/hip_fp16.h>

static inline size_t align256(size_t x) { return (x + 255) & ~size_t(255); }

#define CAP 36864   // per-bucket capacity: mean 32768, sigma ~181 -> +22 sigma

// ---- scatter edges into fixed-capacity buckets, 4B packed (dst_local<<18 | src) ----
// 1024 threads x 16 edges = 16384 edges/block; int2-paired edge loads.
__global__ __launch_bounds__(1024) void k_scatter(const int* __restrict__ ei,
                                                  int* __restrict__ bcursor,
                                                  unsigned* __restrict__ bdata, int E) {
    __shared__ int lcount[256];
    __shared__ int gbase[256];
    int t = threadIdx.x;
    if (t < 256) lcount[t] = 0;
    __syncthreads();
    int chunk = blockIdx.x * 16384;
    int srcv[16], bkt[16], rank[16], dl[16];
#pragma unroll
    for (int k = 0; k < 8; ++k) {
        int e = chunk + k * 2048 + 2 * t;   // e even; E even -> e<E implies e+1<E
        int k2 = 2 * k;
        bkt[k2] = -1; bkt[k2 + 1] = -1;
        if (e < E) {
            int2 sp = *(const int2*)(ei + e);
            int2 dp = *(const int2*)(ei + E + e);
            srcv[k2] = sp.x; bkt[k2] = dp.x >> 10; dl[k2] = dp.x & 1023;
            rank[k2] = atomicAdd(&lcount[bkt[k2]], 1);
            srcv[k2 + 1] = sp.y; bkt[k2 + 1] = dp.y >> 10; dl[k2 + 1] = dp.y & 1023;
            rank[k2 + 1] = atomicAdd(&lcount[bkt[k2 + 1]], 1);
        }
    }
    __syncthreads();
    if (t < 256) {
        int c = lcount[t];
        gbase[t] = t * CAP + (c ? atomicAdd(&bcursor[t], c) : 0);
    }
    __syncthreads();
#pragma unroll
    for (int k = 0; k < 16; ++k) {
        if (bkt[k] >= 0)
            bdata[gbase[bkt[k]] + rank[k]] = ((unsigned)dl[k] << 18) | (unsigned)srcv[k];
    }
}

// ---- per-bucket CSR build (bucket-scan folded in): LDS-staged col placement ----
__global__ __launch_bounds__(1024) void k_build(const unsigned* __restrict__ bdata,
                                                const int* __restrict__ bcursor,
                                                int* __restrict__ row_ptr,
                                                float* __restrict__ dinv,
                                                int* __restrict__ col,
                                                const float* __restrict__ x,
                                                float2* __restrict__ xt,
                                                int N, int E, int NBv) {
    __shared__ int curs[1024];
    __shared__ int sums[256];
    __shared__ int bsc[256];
    __shared__ int stage[CAP];          // 147 KB; first 1024 ints double as hist
    int* hist = stage;                  // alias: hist is dead before stage is written
    int bkt = blockIdx.x;
    int t = threadIdx.x;
    // folded bucket scan: tb = sum of counts of buckets < bkt
    if (t < 256) bsc[t] = (t < NBv) ? bcursor[t] : 0;
    __syncthreads();
    for (int off = 1; off < 256; off <<= 1) {
        int xv = 0;
        if (t < 256 && t >= off) xv = bsc[t - off];
        __syncthreads();
        if (t < 256) bsc[t] += xv;
        __syncthreads();
    }
    int count = bcursor[bkt];
    int tb = bsc[bkt] - count;
    int fs = bkt * CAP;                 // fixed storage base
    int node0 = bkt << 10;
    int nn = N - node0; if (nn > 1024) nn = 1024;
    hist[t] = 0;
    __syncthreads();
    for (int e = t; e < count; e += 1024)
        atomicAdd(&hist[bdata[fs + e] >> 18], 1);
    __syncthreads();
    int v0 = 0, v1 = 0, v2 = 0, v3 = 0, s = 0;
    if (t < 256) {
        int b4 = t * 4;
        v0 = hist[b4]; v1 = hist[b4 + 1]; v2 = hist[b4 + 2]; v3 = hist[b4 + 3];
        s = v0 + v1 + v2 + v3;
        sums[t] = s;
    }
    __syncthreads();
    for (int off = 1; off < 256; off <<= 1) {
        int xv = 0;
        if (t < 256 && t >= off) xv = sums[t - off];
        __syncthreads();
        if (t < 256) sums[t] += xv;
        __syncthreads();
    }
    if (t < 256) {
        int b4 = t * 4;
        int e0 = sums[t] - s;           // LOCAL offsets within bucket
        int e1 = e0 + v0, e2 = e1 + v1, e3 = e2 + v2;
        curs[b4] = e0; curs[b4 + 1] = e1; curs[b4 + 2] = e2; curs[b4 + 3] = e3;
        if (b4 < nn)     { row_ptr[node0 + b4]     = tb + e0; dinv[node0 + b4]     = rsqrtf((float)v0 + 1.f); }
        if (b4 + 1 < nn) { row_ptr[node0 + b4 + 1] = tb + e1; dinv[node0 + b4 + 1] = rsqrtf((float)v1 + 1.f); }
        if (b4 + 2 < nn) { row_ptr[node0 + b4 + 2] = tb + e2; dinv[node0 + b4 + 2] = rsqrtf((float)v2 + 1.f); }
        if (b4 + 3 < nn) { row_ptr[node0 + b4 + 3] = tb + e3; dinv[node0 + b4 + 3] = rsqrtf((float)v3 + 1.f); }
    }
    if (bkt == NBv - 1 && t == 0) row_ptr[N] = E;
    __syncthreads();                    // hist reads done; stage may be overwritten
    for (int e = t; e < count; e += 1024) {
        unsigned p = bdata[fs + e];     // second read is L2-hot
        int dl = p >> 18;
        int pos = atomicAdd(&curs[dl], 1);
        stage[pos] = (int)(p & 0x3FFFFu);
    }
    __syncthreads();
    for (int i = t; i < count; i += 1024)
        col[tb + i] = stage[i];         // fully coalesced streaming store
    // fused xt epilogue: xt[node] = x[node] * dinv[node]
    for (int i = t; i < nn; i += 1024) {
        int node = node0 + i;
        float d2 = dinv[node];
        xt[node] = make_float2(x[node * 2] * d2, x[node * 2 + 1] * d2);
    }
}

// ================= conv1: 4 lanes/node, 4-deep pipeline, shfl-reduce, W1+relu -> fp16
__global__ __launch_bounds__(256) void k_conv1_fused(const int* __restrict__ rp,
                                                     const int* __restrict__ col,
                                                     const float2* __restrict__ xt,
                                                     const float* __restrict__ dinv,
                                                     const float* __restrict__ W1,
                                                     const float* __restrict__ b1,
                                                     uint2* __restrict__ ht, int n) {
    int gt = blockIdx.x * 256 + threadIdx.x;
    int node = gt >> 2;       // 64 nodes per block
    int q = gt & 3;           // lane within quad
    if (node >= n) return;
    int rs = rp[node], re = rp[node + 1];
    float a0 = 0.f, a1 = 0.f;
    int e = rs + q;
    for (; e + 12 < re; e += 16) {
        int c0 = __builtin_nontemporal_load(col + e);
        int c1 = __builtin_nontemporal_load(col + e + 4);
        int c2 = __builtin_nontemporal_load(col + e + 8);
        int c3 = __builtin_nontemporal_load(col + e + 12);
        float2 v0 = xt[c0];
        float2 v1 = xt[c1];
        float2 v2 = xt[c2];
        float2 v3 = xt[c3];
        a0 += (v0.x + v1.x) + (v2.x + v3.x);
        a1 += (v0.y + v1.y) + (v2.y + v3.y);
    }
    for (; e < re; e += 4) {
        float2 v = xt[__builtin_nontemporal_load(col + e)];
        a0 += v.x; a1 += v.y;
    }
    if (q == 0) { float2 sf = xt[node]; a0 += sf.x; a1 += sf.y; }  // self loop
    a0 += __shfl_xor(a0, 1); a0 += __shfl_xor(a0, 2);
    a1 += __shfl_xor(a1, 1); a1 += __shfl_xor(a1, 2);
    float dv = dinv[node];
    a0 *= dv; a1 *= dv;
    int f0 = q * 4;
    float v0 = fmaxf(a0 * W1[f0]     + a1 * W1[16 + f0]     + b1[f0],     0.f) * dv;
    float v1 = fmaxf(a0 * W1[f0 + 1] + a1 * W1[16 + f0 + 1] + b1[f0 + 1], 0.f) * dv;
    float v2 = fmaxf(a0 * W1[f0 + 2] + a1 * W1[16 + f0 + 2] + b1[f0 + 2], 0.f) * dv;
    float v3 = fmaxf(a0 * W1[f0 + 3] + a1 * W1[16 + f0 + 3] + b1[f0 + 3], 0.f) * dv;
    __half2 h0 = __floats2half2_rn(v0, v1);
    __half2 h1 = __floats2half2_rn(v2, v3);
    uint2 w;
    w.x = *reinterpret_cast<unsigned*>(&h0);
    w.y = *reinterpret_cast<unsigned*>(&h1);
    ht[(size_t)node * 4 + q] = w;   // quad writes 32B contiguous
}

// ================= conv2 gather: zero-LDS, 8 lanes/node, 16-deep pipeline ==========
__global__ __launch_bounds__(256) void k_gather2(const int* __restrict__ rp,
                                                 const int* __restrict__ col,
                                                 const __half2* __restrict__ ht,
                                                 const float* __restrict__ dinv,
                                                 float* __restrict__ agg, int N) {
    int gt = blockIdx.x * 256 + threadIdx.x;
    int node = gt >> 3;      // 32 nodes per block
    int fq = gt & 7;         // half2 index within 32B row
    if (node >= N) return;
    int rs = rp[node], re = rp[node + 1];
    const __half2* __restrict__ base = ht + fq;   // row stride 8 half2s
    float ax = 0.f, ay = 0.f;
    int e = rs;
    for (; e + 16 <= re; e += 16) {
        int c[16];
#pragma unroll
        for (int k = 0; k < 16; ++k) c[k] = __builtin_nontemporal_load(col + e + k);
        float2 v[16];
#pragma unroll
        for (int k = 0; k < 16; ++k) v[k] = __half22float2(base[(size_t)c[k] * 8]);
#pragma unroll
        for (int k = 0; k < 16; ++k) { ax += v[k].x; ay += v[k].y; }
    }
    for (; e + 8 <= re; e += 8) {
        int c[8];
#pragma unroll
        for (int k = 0; k < 8; ++k) c[k] = __builtin_nontemporal_load(col + e + k);
        float2 v[8];
#pragma unroll
        for (int k = 0; k < 8; ++k) v[k] = __half22float2(base[(size_t)c[k] * 8]);
#pragma unroll
        for (int k = 0; k < 8; ++k) { ax += v[k].x; ay += v[k].y; }
    }
    for (; e < re; ++e) {
        float2 v = __half22float2(base[(size_t)col[e] * 8]);
        ax += v.x; ay += v.y;
    }
    {   // self loop
        float2 v = __half22float2(base[(size_t)node * 8]);
        ax += v.x; ay += v.y;
    }
    float dv = dinv[node];
    __builtin_nontemporal_store(ax * dv, agg + (size_t)node * 16 + 2 * fq);
    __builtin_nontemporal_store(ay * dv, agg + (size_t)node * 16 + 2 * fq + 1);
}

// ================= conv2 transform + relu + segmented pool =================
__global__ __launch_bounds__(256) void k_trans_pool(const float* __restrict__ agg,
                                                    const float* __restrict__ W2,
                                                    const float* __restrict__ b2,
                                                    const int* __restrict__ batch,
                                                    float* __restrict__ gsum, int N) {
    __shared__ float aggs[64][17];
    __shared__ float h2s[64][33];
    __shared__ float w2s[512];   // [16][32] row-major
    __shared__ float b2s[32];
    __shared__ int   bids[64];
    int t = threadIdx.x;
    if (t < 128) ((float4*)w2s)[t] = ((const float4*)W2)[t];
    if (t < 32)  b2s[t] = b2[t];
    int node0 = blockIdx.x * 64;
    if (t < 64)  bids[t] = (node0 + t < N) ? batch[node0 + t] : -1;
    {
        int nl = t >> 2, q = t & 3;
        int node = node0 + nl;
        float4 v = make_float4(0.f, 0.f, 0.f, 0.f);
        if (node < N) v = *(const float4*)(agg + (size_t)node * 16 + (size_t)q * 4);
        int c0 = q * 4;
        aggs[nl][c0] = v.x; aggs[nl][c0 + 1] = v.y;
        aggs[nl][c0 + 2] = v.z; aggs[nl][c0 + 3] = v.w;
    }
    __syncthreads();
    {
        int nl = t >> 2;
        int jq = (t & 3) * 8;
        float o[8];
#pragma unroll
        for (int j = 0; j < 8; ++j) o[j] = b2s[jq + j];
#pragma unroll
        for (int k = 0; k < 16; ++k) {
            float a = aggs[nl][k];
#pragma unroll
            for (int j = 0; j < 8; ++j) o[j] += a * w2s[k * 32 + jq + j];
        }
#pragma unroll
        for (int j = 0; j < 8; ++j) h2s[nl][jq + j] = fmaxf(o[j], 0.f);
    }
    __syncthreads();
    // segmented pooling (batch sorted -> few atomics): 4 segs x 32 feats
    if (t < 128) {
        int j = t & 31, seg = t >> 5;
        int nbeg = seg * 16, nend = nbeg + 16;
        float acc = 0.f;
        int cur = bids[nbeg];
        for (int n2 = nbeg; n2 < nend; ++n2) {
            int b = bids[n2];
            if (b != cur) {
                if (cur >= 0) atomicAdd(&gsum[(size_t)cur * 32 + j], acc);
                acc = 0.f; cur = b;
            }
            if (b >= 0) acc += h2s[n2][j];
        }
        if (cur >= 0) atomicAdd(&gsum[(size_t)cur * 32 + j], acc);
    }
}

// ================= final MLP (graph bounds via binary search on sorted batch) ======
__global__ void k_final(const float* __restrict__ gsum, const int* __restrict__ batch,
                        const float* __restrict__ Wfc1, const float* __restrict__ bfc1,
                        const float* __restrict__ Wfc2, const float* __restrict__ bfc2,
                        float* __restrict__ out, int G, int N) {
    int g = blockIdx.x * blockDim.x + threadIdx.x;
    if (g >= G) return;
    int lo = 0, hi = N;
    while (lo < hi) { int m = (lo + hi) >> 1; if (batch[m] < g) lo = m + 1; else hi = m; }
    int s = lo;
    lo = s; hi = N;
    while (lo < hi) { int m = (lo + hi) >> 1; if (batch[m] < g + 1) lo = m + 1; else hi = m; }
    float cnt = (float)(lo - s);
    float inv = 1.f / fmaxf(cnt, 1.f);
    float p[32];
#pragma unroll
    for (int i = 0; i < 32; ++i) p[i] = gsum[(size_t)g * 32 + i] * inv;
    float o = bfc2[0];
#pragma unroll
    for (int j = 0; j < 16; ++j) {
        float a = bfc1[j];
#pragma unroll
        for (int i = 0; i < 32; ++i) a += p[i] * Wfc1[i * 16 + j];
        o += fmaxf(a, 0.f) * Wfc2[j];
    }
    out[g] = o;
}

extern "C" void kernel_launch(void* const* d_in, const int* in_sizes, int n_in,
                              void* d_out, int out_size, void* d_ws, size_t ws_size,
                              hipStream_t stream) {
    const float* x     = (const float*)d_in[0];
    const int*   ei    = (const int*)d_in[1];
    const int*   batch = (const int*)d_in[2];
    const float* W1    = (const float*)d_in[3];
    const float* b1    = (const float*)d_in[4];
    const float* W2    = (const float*)d_in[5];
    const float* b2    = (const float*)d_in[6];
    const float* Wfc1  = (const float*)d_in[7];
    const float* bfc1  = (const float*)d_in[8];
    const float* Wfc2  = (const float*)d_in[9];
    const float* bfc2  = (const float*)d_in[10];
    float* out = (float*)d_out;

    const int N = in_sizes[0] / 2;      // 200000
    const int E = in_sizes[1] / 2;      // 6400000
    const int G = out_size;             // 1000
    const int NBv = (N + 1023) >> 10;   // 196

    // ---- workspace layout (~77 MB); bcursor and gsum adjacent for single memset ----
    char* ws = (char*)d_ws;
    size_t off = 0;
    float* dinv    = (float*)(ws + off); off += align256((size_t)N * 4);
    int*   row_ptr = (int*)(ws + off);   off += align256((size_t)(N + 1) * 4);
    int*   bcursor = (int*)(ws + off);   size_t z0 = off; off += align256(256 * 4);
    float* gsum    = (float*)(ws + off); off += align256((size_t)G * 32 * 4);
    size_t zlen = off - z0;
    float2* xt     = (float2*)(ws + off); off += align256((size_t)N * 8);
    __half2* ht    = (__half2*)(ws + off); off += align256((size_t)N * 32);
    float* agg     = (float*)(ws + off); off += align256((size_t)N * 16 * 4);
    int*   col     = (int*)(ws + off);   off += align256((size_t)E * 4);
    unsigned* bdata = (unsigned*)(ws + off); off += align256((size_t)NBv * CAP * 4);

    const int BS = 256;

    hipMemsetAsync(bcursor, 0, zlen, stream);

    k_scatter<<<(E + 16383) / 16384, 1024, 0, stream>>>(ei, bcursor, bdata, E);
    k_build<<<NBv, 1024, 0, stream>>>(bdata, bcursor, row_ptr, dinv, col, x, xt, N, E, NBv);

    k_conv1_fused<<<((size_t)N * 4 + 255) / 256, 256, 0, stream>>>(row_ptr, col, xt, dinv,
                                                                   W1, b1, (uint2*)ht, N);
    k_gather2<<<((size_t)N * 8 + 255) / 256, 256, 0, stream>>>(row_ptr, col, ht, dinv, agg, N);
    k_trans_pool<<<(N + 63) / 64, 256, 0, stream>>>(agg, W2, b2, batch, gsum, N);

    k_final<<<(G + BS - 1) / BS, BS, 0, stream>>>(gsum, batch, Wfc1, bfc1, Wfc2, bfc2,
                                                  out, G, N);
}